// Round 12
// baseline (395.921 us; speedup 1.0000x reference)
//
#include <hip/hip_runtime.h>
#include <hip/hip_bf16.h>
#include <math.h>

#define BB 512
#define SS 128
#define DD 256
#define HH 4
#define TOPK 8
#define D3 768
#define DMA 248
#define ACT_ 8
#define NTOK 65536            // B*S

typedef __attribute__((ext_vector_type(8))) short bf16x8;
typedef __attribute__((ext_vector_type(4))) short short4v;
typedef __attribute__((ext_vector_type(4))) float f32x4;

static __device__ __forceinline__ short f2bf(float x) {
    __hip_bfloat16 h = __float2bfloat16(x);
    return *reinterpret_cast<short*>(&h);
}
static __device__ __forceinline__ float bf2f(short s) {
    __hip_bfloat16 h = *reinterpret_cast<__hip_bfloat16*>(&s);
    return __bfloat162float(h);
}
static __device__ __forceinline__ float tanh_fast(float x) {
    float e = __expf(2.f * x);
    return 1.f - 2.f / (e + 1.f);
}

// ---------------------------------------------------------------------------
// device helpers for the merged prep kernel
// ---------------------------------------------------------------------------
__device__ __forceinline__ void dev_wsplit(float (*t)[33], const float* src,
        short* dhi, short* dlo, int R, int C, int Cpad, int blk, int tid) {
    const int ctiles = Cpad >> 5;
    const int rt = blk / ctiles, ct = blk % ctiles;
    const int r0 = rt * 32, c0 = ct * 32;
#pragma unroll
    for (int i = 0; i < 4; ++i) {
        int idx = i * 256 + tid;
        int lr = idx >> 5, lc = idx & 31;
        t[lr][lc] = (c0 + lc < C) ? src[(size_t)(r0 + lr) * C + c0 + lc] : 0.f;
    }
    __syncthreads();
#pragma unroll
    for (int i = 0; i < 4; ++i) {
        int idx = i * 256 + tid;
        int lc = idx >> 5, lr = idx & 31;
        float v = t[lr][lc];
        short h = f2bf(v);
        size_t o = (size_t)(c0 + lc) * R + r0 + lr;
        dhi[o] = h;
        dlo[o] = f2bf(v - bf2f(h));
    }
}

__device__ __forceinline__ void dev_trbf(float (*t)[33], const float* src,
        __hip_bfloat16* dst, int R, int C, int blk, int tid) {
    const int ctiles = C >> 5;
    const int rt = blk / ctiles, ct = blk % ctiles;
    const int r0 = rt * 32, c0 = ct * 32;
#pragma unroll
    for (int i = 0; i < 4; ++i) {
        int idx = i * 256 + tid;
        int lr = idx >> 5, lc = idx & 31;
        t[lr][lc] = src[(size_t)(r0 + lr) * C + c0 + lc];
    }
    __syncthreads();
#pragma unroll
    for (int i = 0; i < 4; ++i) {
        int idx = i * 256 + tid;
        int lc = idx >> 5, lr = idx & 31;
        dst[(size_t)(c0 + lc) * R + r0 + lr] = __float2bfloat16(t[lr][lc]);
    }
}

__device__ __forceinline__ void dev_prep(float (*t)[33], const float* Wqkv,
        float* WqT, short* WqTbf, __hip_bfloat16* WkvT, int blk, int tid) {
    const int rt = blk / 24, ct = blk % 24;
    const int r0 = rt * 32, c0 = ct * 32;
#pragma unroll
    for (int i = 0; i < 4; ++i) {
        int idx = i * 256 + tid;
        int lr = idx >> 5, lc = idx & 31;
        t[lr][lc] = Wqkv[(size_t)(r0 + lr) * D3 + c0 + lc];
    }
    __syncthreads();
#pragma unroll
    for (int i = 0; i < 4; ++i) {
        int idx = i * 256 + tid;
        int lc = idx >> 5, lr = idx & 31;
        float v = t[lr][lc];
        int c = c0 + lc, r = r0 + lr;
        if (c < 256) {
            WqT[(size_t)c * 256 + r] = v;
            WqTbf[(size_t)c * 256 + r] = f2bf(v);
        } else {
            WkvT[(size_t)(c - 256) * 256 + r] = __float2bfloat16(v);
        }
    }
}

// ---------------------------------------------------------------------------
// K_prepall: all weight transposes/splits + pdcast in ONE launch.
// ---------------------------------------------------------------------------
__global__ void __launch_bounds__(256) k_prepall(
        const float* __restrict__ W1, short* __restrict__ W1Thi, short* __restrict__ W1Tlo,
        const float* __restrict__ W2, short* __restrict__ W2Thi, short* __restrict__ W2Tlo,
        const float* __restrict__ Wqkv, float* __restrict__ WqT, short* __restrict__ WqTbf,
        __hip_bfloat16* __restrict__ WkvT,
        const float* __restrict__ W_ih, __hip_bfloat16* __restrict__ WihT,
        const float* __restrict__ W_hh, __hip_bfloat16* __restrict__ WhhT,
        const float* __restrict__ Wo, __hip_bfloat16* __restrict__ WoT,
        const float* __restrict__ prev_d, __hip_bfloat16* __restrict__ pdbf) {
    __shared__ float t[32][33];
    const int blk = blockIdx.x, tid = threadIdx.x;
    if (blk < 16)        dev_wsplit(t, W1, W1Thi, W1Tlo, 64, 256, 256, blk, tid);
    else if (blk < 80)   dev_wsplit(t, W2, W2Thi, W2Tlo, 256, DMA, 256, blk - 16, tid);
    else if (blk < 272)  dev_prep(t, Wqkv, WqT, WqTbf, WkvT, blk - 80, tid);
    else if (blk < 1808) dev_trbf(t, W_ih, WihT, 2048, 768, blk - 272, tid);
    else if (blk < 2000) dev_trbf(t, W_hh, WhhT, 256, 768, blk - 1808, tid);
    else if (blk < 2064) dev_trbf(t, Wo, WoT, 256, 256, blk - 2000, tid);
    else {
        int i = (blk - 2064) * 1024 + tid * 4;
        float4 v = *(const float4*)&prev_d[i];
        pdbf[i]     = __float2bfloat16(v.x);
        pdbf[i + 1] = __float2bfloat16(v.y);
        pdbf[i + 2] = __float2bfloat16(v.z);
        pdbf[i + 3] = __float2bfloat16(v.w);
    }
}

// ---------------------------------------------------------------------------
// K_mlp: FUSED MLP, GEMM2 B-frags double-buffered (latency pipeline).
// ---------------------------------------------------------------------------
__global__ void __launch_bounds__(256) k_mlp(const float* __restrict__ x_obs,
        const short* __restrict__ W1Thi, const short* __restrict__ W1Tlo,
        const float* __restrict__ b1,
        const short* __restrict__ W2Thi, const short* __restrict__ W2Tlo,
        const float* __restrict__ b2, const float* __restrict__ a_prev,
        float* __restrict__ xa) {
    __shared__ __attribute__((aligned(16))) short Hhi[32 * 264];
    __shared__ __attribute__((aligned(16))) short Hlo[32 * 264];
    const int m0 = blockIdx.x * 32;
    const int tid = threadIdx.x;
    const int wave = tid >> 6, lane = tid & 63;
    const int quad = lane >> 4, l15 = lane & 15;
    const int n0 = wave * 64;

    // ---- GEMM1: h strip [32 tokens x 64 cols] ----
    {
        bf16x8 Bh[4][2], Bl[4][2];
#pragma unroll
        for (int nt = 0; nt < 4; ++nt)
#pragma unroll
            for (int ks = 0; ks < 2; ++ks) {
                size_t o = (size_t)(n0 + nt * 16 + l15) * 64 + ks * 32 + quad * 8;
                Bh[nt][ks] = *(const bf16x8*)&W1Thi[o];
                Bl[nt][ks] = *(const bf16x8*)&W1Tlo[o];
            }
        f32x4 acc[2][4];
#pragma unroll
        for (int mt = 0; mt < 2; ++mt)
#pragma unroll
            for (int nt = 0; nt < 4; ++nt) acc[mt][nt] = (f32x4){0.f, 0.f, 0.f, 0.f};
#pragma unroll
        for (int mt = 0; mt < 2; ++mt) {
            bf16x8 Ah[2], Al[2];
#pragma unroll
            for (int ks = 0; ks < 2; ++ks) {
                const float* xp = &x_obs[(size_t)(m0 + mt * 16 + l15) * 64 + ks * 32 + quad * 8];
                float4 a0 = *(const float4*)xp;
                float4 a1 = *(const float4*)(xp + 4);
                bf16x8 h, l;
                h[0]=f2bf(a0.x); l[0]=f2bf(a0.x - bf2f(h[0]));
                h[1]=f2bf(a0.y); l[1]=f2bf(a0.y - bf2f(h[1]));
                h[2]=f2bf(a0.z); l[2]=f2bf(a0.z - bf2f(h[2]));
                h[3]=f2bf(a0.w); l[3]=f2bf(a0.w - bf2f(h[3]));
                h[4]=f2bf(a1.x); l[4]=f2bf(a1.x - bf2f(h[4]));
                h[5]=f2bf(a1.y); l[5]=f2bf(a1.y - bf2f(h[5]));
                h[6]=f2bf(a1.z); l[6]=f2bf(a1.z - bf2f(h[6]));
                h[7]=f2bf(a1.w); l[7]=f2bf(a1.w - bf2f(h[7]));
                Ah[ks] = h; Al[ks] = l;
            }
#pragma unroll
            for (int nt = 0; nt < 4; ++nt)
#pragma unroll
                for (int ks = 0; ks < 2; ++ks) {
                    acc[mt][nt] = __builtin_amdgcn_mfma_f32_16x16x32_bf16(Ah[ks], Bh[nt][ks], acc[mt][nt], 0, 0, 0);
                    acc[mt][nt] = __builtin_amdgcn_mfma_f32_16x16x32_bf16(Ah[ks], Bl[nt][ks], acc[mt][nt], 0, 0, 0);
                    acc[mt][nt] = __builtin_amdgcn_mfma_f32_16x16x32_bf16(Al[ks], Bh[nt][ks], acc[mt][nt], 0, 0, 0);
                }
        }
#pragma unroll
        for (int nt = 0; nt < 4; ++nt) {
            int col = n0 + nt * 16 + l15;
            float bias = b1[col];
#pragma unroll
            for (int mt = 0; mt < 2; ++mt)
#pragma unroll
                for (int r = 0; r < 4; ++r) {
                    int tl = mt * 16 + quad * 4 + r;       // local token
                    float tv = tanh_fast(acc[mt][nt][r] + bias);
                    short h = f2bf(tv);
                    Hhi[tl * 264 + col] = h;
                    Hlo[tl * 264 + col] = f2bf(tv - bf2f(h));
                }
        }
    }

    // ---- GEMM2: double-buffered B; k0=0 preload overlaps the barrier ----
    f32x4 acc[2][4];
#pragma unroll
    for (int mt = 0; mt < 2; ++mt)
#pragma unroll
        for (int nt = 0; nt < 4; ++nt) acc[mt][nt] = (f32x4){0.f, 0.f, 0.f, 0.f};

    bf16x8 Bh[2][4], Bl[2][4];
#pragma unroll
    for (int nt = 0; nt < 4; ++nt) {
        size_t o = (size_t)(n0 + nt * 16 + l15) * 256 + quad * 8;
        Bh[0][nt] = *(const bf16x8*)&W2Thi[o];
        Bl[0][nt] = *(const bf16x8*)&W2Tlo[o];
    }
    __syncthreads();

#pragma unroll
    for (int ki = 0; ki < 8; ++ki) {
        const int cur = ki & 1, nxt = cur ^ 1;
        if (ki < 7) {
            int k0n = (ki + 1) * 32;
#pragma unroll
            for (int nt = 0; nt < 4; ++nt) {
                size_t o = (size_t)(n0 + nt * 16 + l15) * 256 + k0n + quad * 8;
                Bh[nxt][nt] = *(const bf16x8*)&W2Thi[o];
                Bl[nxt][nt] = *(const bf16x8*)&W2Tlo[o];
            }
        }
        const int k0 = ki * 32;
#pragma unroll
        for (int mt = 0; mt < 2; ++mt) {
            bf16x8 Ah = *(bf16x8*)&Hhi[(mt * 16 + l15) * 264 + k0 + quad * 8];
            bf16x8 Al = *(bf16x8*)&Hlo[(mt * 16 + l15) * 264 + k0 + quad * 8];
#pragma unroll
            for (int nt = 0; nt < 4; ++nt) {
                acc[mt][nt] = __builtin_amdgcn_mfma_f32_16x16x32_bf16(Ah, Bh[cur][nt], acc[mt][nt], 0, 0, 0);
                acc[mt][nt] = __builtin_amdgcn_mfma_f32_16x16x32_bf16(Ah, Bl[cur][nt], acc[mt][nt], 0, 0, 0);
                acc[mt][nt] = __builtin_amdgcn_mfma_f32_16x16x32_bf16(Al, Bh[cur][nt], acc[mt][nt], 0, 0, 0);
            }
        }
    }
#pragma unroll
    for (int nt = 0; nt < 4; ++nt) {
        int col = n0 + nt * 16 + l15;
        float bias = (col < DMA) ? b2[col] : 0.f;
#pragma unroll
        for (int mt = 0; mt < 2; ++mt)
#pragma unroll
            for (int r = 0; r < 4; ++r) {
                int token = m0 + mt * 16 + quad * 4 + r;
                float v;
                if (col < DMA) v = acc[mt][nt][r] + bias;
                else           v = a_prev[(size_t)token * ACT_ + (col - DMA)];
                xa[(size_t)token * 256 + col] = v;
            }
    }
}

// ---------------------------------------------------------------------------
// K_skv: fused (independent) score + kvmm. blocks [0,1024): kvmm per
// (b, mhalf); blocks [1024,1536): score per b. LDS unioned.
// ---------------------------------------------------------------------------
__global__ void __launch_bounds__(256) k_skv(const float* __restrict__ xa,
        const float* __restrict__ Wqkv, const float* __restrict__ WqT,
        const float* __restrict__ bqkv, const short* __restrict__ WkvT,
        int* __restrict__ idxb,
        __hip_bfloat16* __restrict__ kbf, __hip_bfloat16* __restrict__ vbfT) {
    __shared__ __attribute__((aligned(16))) short smem[64 * 264];   // 33.8 KB
    const int tid = threadIdx.x;

    if (blockIdx.x < 1024) {
        // ---------------- kvmm body (R8-verified) ----------------
        short* Ash = smem;
        const int b = blockIdx.x >> 1, m0 = (blockIdx.x & 1) * 64;
        const int wave = tid >> 6, lane = tid & 63;
        const int quad = lane >> 4, l15 = lane & 15;
        const float* xab = xa + ((size_t)b * SS + m0) * DD;

#pragma unroll
        for (int it = 0; it < 16; ++it) {
            int idx = it * 256 + tid;
            int row = idx >> 6, c4 = (idx & 63) * 4;
            float4 x4 = *(const float4*)&xab[(size_t)row * 256 + c4];
            short4v sv = { f2bf(x4.x), f2bf(x4.y), f2bf(x4.z), f2bf(x4.w) };
            *(short4v*)&Ash[row * 264 + c4] = sv;
        }
        __syncthreads();

        for (int ntile = 0; ntile < 4; ++ntile) {
            const int nbase = ntile * 128 + wave * 32;
            f32x4 acc[4][2];
#pragma unroll
            for (int nf = 0; nf < 2; ++nf) {
                float bias = bqkv[256 + nbase + nf * 16 + l15];
#pragma unroll
                for (int mt = 0; mt < 4; ++mt)
                    acc[mt][nf] = (f32x4){bias, bias, bias, bias};
            }
#pragma unroll
            for (int k0 = 0; k0 < 256; k0 += 32) {
                bf16x8 af[4], bf[2];
#pragma unroll
                for (int mt = 0; mt < 4; ++mt)
                    af[mt] = *(bf16x8*)&Ash[(mt * 16 + l15) * 264 + k0 + quad * 8];
#pragma unroll
                for (int nf = 0; nf < 2; ++nf)
                    bf[nf] = *(const bf16x8*)&WkvT[(size_t)(nbase + nf * 16 + l15) * 256 + k0 + quad * 8];
#pragma unroll
                for (int mt = 0; mt < 4; ++mt)
#pragma unroll
                    for (int nf = 0; nf < 2; ++nf)
                        acc[mt][nf] = __builtin_amdgcn_mfma_f32_16x16x32_bf16(
                            af[mt], bf[nf], acc[mt][nf], 0, 0, 0);
            }
#pragma unroll
            for (int nf = 0; nf < 2; ++nf) {
                int n_g = nbase + nf * 16 + l15;
#pragma unroll
                for (int mt = 0; mt < 4; ++mt)
#pragma unroll
                    for (int r = 0; r < 4; ++r) {
                        int token = m0 + mt * 16 + quad * 4 + r;
                        if (n_g < 256)
                            kbf[((size_t)b * SS + token) * 256 + n_g] = __float2bfloat16(acc[mt][nf][r]);
                        else
                            vbfT[((size_t)b * 256 + (n_g - 256)) * SS + token] = __float2bfloat16(acc[mt][nf][r]);
                    }
            }
        }
    } else {
        // ---------------- score body (R4-verified identity path) ----------------
        float* xasum_sh = (float*)smem;          // 256 f
        float* ksum_sh  = xasum_sh + 256;        // 256 f
        float* wqk_sh   = xasum_sh + 512;        // 256 f
        double* ssd     = (double*)(xasum_sh + 768);  // 128 d (offset 3072, 16-aligned)
        const int b = blockIdx.x - 1024;
        const float* xab = xa + (size_t)b * SS * DD;

        float s = 0.f;
        for (int r = 0; r < 128; ++r) s += xab[r * 256 + tid];
        xasum_sh[tid] = s;
        __syncthreads();

        float ks = 128.f * bqkv[256 + tid];
        for (int d = 0; d < 256; ++d)
            ks = fmaf(xasum_sh[d], Wqkv[(size_t)d * D3 + 256 + tid], ks);
        ksum_sh[tid] = ks;
        __syncthreads();

        float wq = 0.f;
        for (int c = 0; c < 256; ++c)
            wq = fmaf(WqT[(size_t)c * 256 + tid], ksum_sh[c], wq);
        wqk_sh[tid] = wq;
        double bqdot = 0.0;
        for (int c = 0; c < 256; ++c)
            bqdot += (double)bqkv[c] * (double)ksum_sh[c];
        __syncthreads();

        {
            int r = tid >> 1, half = tid & 1;
            const float* xr = xab + (size_t)r * 256 + half * 128;
            const float* wk = wqk_sh + half * 128;
            double sd = 0.0;
            for (int d2 = 0; d2 < 128; ++d2) sd += (double)xr[d2] * (double)wk[d2];
            double so = __shfl_xor(sd, 1);
            if (half == 0) ssd[r] = (sd + so + bqdot) * 0.125;
        }
        __syncthreads();
        if (tid < 64) {
            double v0 = ssd[tid], v1 = ssd[tid + 64];
            int i0 = tid, i1 = tid + 64;
            bool t0 = false, t1 = false;
            for (int t = 0; t < TOPK; ++t) {
                double c0 = t0 ? -1e300 : v0;
                double c1 = t1 ? -1e300 : v1;
                double bvv; int bi;
                if (c1 > c0) { bvv = c1; bi = i1; } else { bvv = c0; bi = i0; }
#pragma unroll
                for (int off = 1; off < 64; off <<= 1) {
                    double ov = __shfl_xor(bvv, off);
                    int oi = __shfl_xor(bi, off);
                    if (ov > bvv || (ov == bvv && oi < bi)) { bvv = ov; bi = oi; }
                }
                if (tid == 0) idxb[b * TOPK + t] = bi;
                if (bi == i0) t0 = true;
                if (bi == i1) t1 = true;
            }
        }
    }
}

// ---------------------------------------------------------------------------
// K_attn2: gather + q-projection + attention fused, per batch. Wave = head.
// gather xa rows -> Xsh (bf16) -> per-wave q-GEMM -> Qsh (wave-local) ->
// MFMA QK^T -> in-reg softmax -> Pbuf -> MFMA PV -> Ctx.
// ---------------------------------------------------------------------------
__global__ void __launch_bounds__(256) k_attn2(const float* __restrict__ xa,
        const int* __restrict__ idxb, const short* __restrict__ WqTbf,
        const float* __restrict__ bqkv,
        const short* __restrict__ kbf, const short* __restrict__ vbfT,
        short* __restrict__ Ctx) {
    __shared__ __attribute__((aligned(16))) short Xsh[16 * 264];
    __shared__ __attribute__((aligned(16))) short Qsh[16 * 264];
    __shared__ short Pbuf[4][16 * 136];
    __shared__ int sidx[8];
    const int b = blockIdx.x;
    const int tid = threadIdx.x;
    const int h = tid >> 6, lane = tid & 63;
    const int quad = lane >> 4, l15 = lane & 15;

    if (tid < 8) sidx[tid] = idxb[b * TOPK + tid];
    __syncthreads();
#pragma unroll
    for (int t = 0; t < 16; ++t) {
        short v = 0;
        if (t < 8) v = f2bf(xa[((size_t)b * SS + sidx[t]) * 256 + tid]);
        Xsh[t * 264 + tid] = v;
    }
    __syncthreads();

    // ---- per-wave q-GEMM: wave h computes q cols [h*64, h*64+64) ----
    {
        f32x4 qacc[4];
#pragma unroll
        for (int nt = 0; nt < 4; ++nt) qacc[nt] = (f32x4){0.f, 0.f, 0.f, 0.f};
#pragma unroll
        for (int ki = 0; ki < 8; ++ki) {
            int k0 = ki * 32;
            bf16x8 Ax = *(bf16x8*)&Xsh[l15 * 264 + k0 + quad * 8];
#pragma unroll
            for (int nt = 0; nt < 4; ++nt) {
                int col = h * 64 + nt * 16 + l15;
                bf16x8 Bq = *(const bf16x8*)&WqTbf[(size_t)col * 256 + k0 + quad * 8];
                qacc[nt] = __builtin_amdgcn_mfma_f32_16x16x32_bf16(Ax, Bq, qacc[nt], 0, 0, 0);
            }
        }
#pragma unroll
        for (int nt = 0; nt < 4; ++nt) {
            int col = h * 64 + nt * 16 + l15;
            float bq = bqkv[col];
#pragma unroll
            for (int r = 0; r < 4; ++r)
                Qsh[(quad * 4 + r) * 264 + col] = f2bf(qacc[nt][r] + bq);
        }
    }
    // Qsh strip is wave-local (written & read by wave h only) — no barrier.

    const short* kb = kbf + (size_t)b * SS * 256 + h * 64;
    const short* vb = vbfT + ((size_t)b * 256 + h * 64) * SS;

    bf16x8 aq[2];
#pragma unroll
    for (int ks = 0; ks < 2; ++ks)
        aq[ks] = *(bf16x8*)&Qsh[l15 * 264 + h * 64 + ks * 32 + quad * 8];
    f32x4 sc[8];
#pragma unroll
    for (int nt = 0; nt < 8; ++nt) sc[nt] = (f32x4){0.f, 0.f, 0.f, 0.f};
#pragma unroll
    for (int nt = 0; nt < 8; ++nt)
#pragma unroll
        for (int ks = 0; ks < 2; ++ks) {
            bf16x8 bk = *(const bf16x8*)&kb[(size_t)(nt * 16 + l15) * 256 + ks * 32 + quad * 8];
            sc[nt] = __builtin_amdgcn_mfma_f32_16x16x32_bf16(aq[ks], bk, sc[nt], 0, 0, 0);
        }
#pragma unroll
    for (int r = 0; r < 4; ++r) {
        float m = -3.4e38f;
#pragma unroll
        for (int nt = 0; nt < 8; ++nt) m = fmaxf(m, sc[nt][r]);
        m = fmaxf(m, __shfl_xor(m, 1));
        m = fmaxf(m, __shfl_xor(m, 2));
        m = fmaxf(m, __shfl_xor(m, 4));
        m = fmaxf(m, __shfl_xor(m, 8));
        float s = 0.f;
#pragma unroll
        for (int nt = 0; nt < 8; ++nt) {
            float e = __expf((sc[nt][r] - m) * 0.125f);
            sc[nt][r] = e;
            s += e;
        }
        s += __shfl_xor(s, 1);
        s += __shfl_xor(s, 2);
        s += __shfl_xor(s, 4);
        s += __shfl_xor(s, 8);
        float inv = 1.f / s;
        int row = quad * 4 + r;
#pragma unroll
        for (int nt = 0; nt < 8; ++nt)
            Pbuf[h][row * 136 + nt * 16 + l15] = f2bf(sc[nt][r] * inv);
    }
    __syncthreads();
    bf16x8 ap[4];
#pragma unroll
    for (int ks = 0; ks < 4; ++ks)
        ap[ks] = *(bf16x8*)&Pbuf[h][l15 * 136 + ks * 32 + quad * 8];
    f32x4 ct[4];
#pragma unroll
    for (int nt = 0; nt < 4; ++nt) ct[nt] = (f32x4){0.f, 0.f, 0.f, 0.f};
#pragma unroll
    for (int nt = 0; nt < 4; ++nt)
#pragma unroll
        for (int ks = 0; ks < 4; ++ks) {
            bf16x8 bv = *(const bf16x8*)&vb[(size_t)(nt * 16 + l15) * SS + ks * 32 + quad * 8];
            ct[nt] = __builtin_amdgcn_mfma_f32_16x16x32_bf16(ap[ks], bv, ct[nt], 0, 0, 0);
        }
#pragma unroll
    for (int nt = 0; nt < 4; ++nt)
#pragma unroll
        for (int r = 0; r < 4; ++r)
            Ctx[((size_t)b * 16 + quad * 4 + r) * 256 + h * 64 + nt * 16 + l15] =
                f2bf(ct[nt][r]);
}

// ---------------------------------------------------------------------------
// K_omm: resh = Ctx @ WoT^T + bo. Writes fp32 resh (d_out) + bf16 resh_bf.
// ---------------------------------------------------------------------------
__global__ void __launch_bounds__(256) k_omm(const short* __restrict__ A,
        const short* __restrict__ BT, const float* __restrict__ bias,
        float* __restrict__ resh_out, __hip_bfloat16* __restrict__ resh_bf) {
    __shared__ __attribute__((aligned(16))) short Ash[128 * 72];
    __shared__ __attribute__((aligned(16))) short Bsh[128 * 72];
    const int mt = blockIdx.x >> 1, nt2 = blockIdx.x & 1;
    const int m0 = mt * 128, n0 = nt2 * 128;
    const int tid = threadIdx.x;
    const int wave = tid >> 6, lane = tid & 63;
    const int wm = wave >> 1, wn = wave & 1;
    const int quad = lane >> 4, l15 = lane & 15;

    f32x4 acc[4][4];
#pragma unroll
    for (int tm = 0; tm < 4; ++tm)
#pragma unroll
        for (int tn = 0; tn < 4; ++tn) acc[tm][tn] = (f32x4){0.f, 0.f, 0.f, 0.f};

    for (int k0 = 0; k0 < 256; k0 += 64) {
        __syncthreads();
#pragma unroll
        for (int it = 0; it < 4; ++it) {
            int idx = it * 256 + tid;
            int row = idx >> 3, c8 = idx & 7;
            *(uint4*)&Ash[row * 72 + c8 * 8] =
                *(const uint4*)&A[(size_t)(m0 + row) * 256 + k0 + c8 * 8];
            *(uint4*)&Bsh[row * 72 + c8 * 8] =
                *(const uint4*)&BT[(size_t)(n0 + row) * 256 + k0 + c8 * 8];
        }
        __syncthreads();
#pragma unroll
        for (int ks = 0; ks < 2; ++ks) {
            bf16x8 af[4], bfr[4];
#pragma unroll
            for (int t = 0; t < 4; ++t) {
                af[t]  = *(bf16x8*)&Ash[(wm * 64 + t * 16 + l15) * 72 + ks * 32 + quad * 8];
                bfr[t] = *(bf16x8*)&Bsh[(wn * 64 + t * 16 + l15) * 72 + ks * 32 + quad * 8];
            }
#pragma unroll
            for (int tm = 0; tm < 4; ++tm)
#pragma unroll
                for (int tn = 0; tn < 4; ++tn)
                    acc[tm][tn] = __builtin_amdgcn_mfma_f32_16x16x32_bf16(
                        af[tm], bfr[tn], acc[tm][tn], 0, 0, 0);
        }
    }
#pragma unroll
    for (int tm = 0; tm < 4; ++tm)
#pragma unroll
        for (int tn = 0; tn < 4; ++tn) {
            int col = n0 + wn * 64 + tn * 16 + l15;
            float bv = bias[col];
#pragma unroll
            for (int r = 0; r < 4; ++r) {
                int row = m0 + wm * 64 + tm * 16 + quad * 4 + r;
                int bidx = row >> 4, r16 = row & 15;
                if (r16 < 8) {
                    float v = acc[tm][tn][r] + bv;
                    size_t o = (size_t)bidx * 2048 + r16 * 256 + col;
                    resh_out[o] = v;
                    resh_bf[o] = __float2bfloat16(v);
                }
            }
        }
}

// ---------------------------------------------------------------------------
// K_gru2: both GRU GEMMs in one launch. blocks [0,24): gi (K=2048);
// blocks [24,48): gh (K=256). N=768, 128x128 tiles.
// ---------------------------------------------------------------------------
__global__ void __launch_bounds__(256) k_gru2(const __hip_bfloat16* __restrict__ resh_bf,
        const __hip_bfloat16* __restrict__ WihT, const __hip_bfloat16* __restrict__ pdbf,
        const __hip_bfloat16* __restrict__ WhhT, float* __restrict__ gi,
        float* __restrict__ gh) {
    __shared__ __attribute__((aligned(16))) short Ash[128 * 72];
    __shared__ __attribute__((aligned(16))) short Bsh[128 * 72];
    int blk = blockIdx.x;
    const __hip_bfloat16 *A, *BT;
    float* C;
    int K;
    if (blk < 24) { A = resh_bf; BT = WihT; C = gi; K = 2048; }
    else          { blk -= 24; A = pdbf; BT = WhhT; C = gh; K = 256; }
    const int mt = blk / 6, nt = blk % 6;
    const int m0 = mt * 128, n0 = nt * 128;
    const int tid = threadIdx.x;
    const int wave = tid >> 6, lane = tid & 63;
    const int wm = wave >> 1, wn = wave & 1;
    const int quad = lane >> 4, l15 = lane & 15;

    f32x4 acc[4][4];
#pragma unroll
    for (int tm = 0; tm < 4; ++tm)
#pragma unroll
        for (int tn = 0; tn < 4; ++tn)
            acc[tm][tn] = (f32x4){0.f, 0.f, 0.f, 0.f};

    for (int k0 = 0; k0 < K; k0 += 64) {
        __syncthreads();
#pragma unroll
        for (int it = 0; it < 4; ++it) {
            int idx = it * 256 + tid;
            int row = idx >> 3, c8 = idx & 7;
            *(uint4*)&Ash[row * 72 + c8 * 8] =
                *(const uint4*)&A[(size_t)(m0 + row) * K + k0 + c8 * 8];
            *(uint4*)&Bsh[row * 72 + c8 * 8] =
                *(const uint4*)&BT[(size_t)(n0 + row) * K + k0 + c8 * 8];
        }
        __syncthreads();
#pragma unroll
        for (int ks = 0; ks < 2; ++ks) {
            bf16x8 af[4], bfr[4];
#pragma unroll
            for (int t = 0; t < 4; ++t) {
                af[t]  = *(bf16x8*)&Ash[(wm * 64 + t * 16 + l15) * 72 + ks * 32 + quad * 8];
                bfr[t] = *(bf16x8*)&Bsh[(wn * 64 + t * 16 + l15) * 72 + ks * 32 + quad * 8];
            }
#pragma unroll
            for (int tm = 0; tm < 4; ++tm)
#pragma unroll
                for (int tn = 0; tn < 4; ++tn)
                    acc[tm][tn] = __builtin_amdgcn_mfma_f32_16x16x32_bf16(
                        af[tm], bfr[tn], acc[tm][tn], 0, 0, 0);
        }
    }
#pragma unroll
    for (int tm = 0; tm < 4; ++tm)
#pragma unroll
        for (int tn = 0; tn < 4; ++tn) {
            int col = n0 + wn * 64 + tn * 16 + l15;
#pragma unroll
            for (int r = 0; r < 4; ++r) {
                int row = m0 + wm * 64 + tm * 16 + quad * 4 + r;
                C[(size_t)row * 768 + col] = acc[tm][tn][r];
            }
        }
}

// ---------------------------------------------------------------------------
// K_gruact: gates elementwise. newd = (1-z)*n + z*prev_d
// ---------------------------------------------------------------------------
__global__ void k_gruact(const float* __restrict__ gi, const float* __restrict__ gh,
                         const float* __restrict__ b_ih, const float* __restrict__ b_hh,
                         const float* __restrict__ prev_d, float* __restrict__ newd) {
    const int b = blockIdx.x, tid = threadIdx.x;
    const float* gib = gi + (size_t)b * D3;
    const float* ghb = gh + (size_t)b * D3;
    float ir = gib[tid] + b_ih[tid];
    float iz = gib[256 + tid] + b_ih[256 + tid];
    float in = gib[512 + tid] + b_ih[512 + tid];
    float hr = ghb[tid] + b_hh[tid];
    float hz = ghb[256 + tid] + b_hh[256 + tid];
    float hn = ghb[512 + tid] + b_hh[512 + tid];
    float pd = prev_d[(size_t)b * 256 + tid];
    float r = 1.f / (1.f + __expf(-(ir + hr)));
    float z = 1.f / (1.f + __expf(-(iz + hz)));
    float n = tanhf(in + r * hn);
    newd[(size_t)b * 256 + tid] = (1.f - z) * n + z * pd;
}

// ---------------------------------------------------------------------------
extern "C" void kernel_launch(void* const* d_in, const int* in_sizes, int n_in,
                              void* d_out, int out_size, void* d_ws, size_t ws_size,
                              hipStream_t stream) {
    const float* prev_d = (const float*)d_in[0];
    const float* x_obs  = (const float*)d_in[1];
    const float* a_prev = (const float*)d_in[2];
    const float* W1     = (const float*)d_in[3];
    const float* b1     = (const float*)d_in[4];
    const float* W2     = (const float*)d_in[5];
    const float* b2     = (const float*)d_in[6];
    const float* Wqkv   = (const float*)d_in[7];
    const float* bqkv   = (const float*)d_in[8];
    const float* Wo     = (const float*)d_in[9];
    const float* bo     = (const float*)d_in[10];
    const float* W_ih   = (const float*)d_in[11];
    const float* b_ih   = (const float*)d_in[12];
    const float* W_hh   = (const float*)d_in[13];
    const float* b_hh   = (const float*)d_in[14];
    float* out = (float*)d_out;

    const size_t NT = (size_t)BB * SS * DD;   // 16,777,216
    // region 1: xa fp32 (67 MB)
    float* xa = (float*)d_ws;
    // region 2 (67 MB): [kbf|vbfT]; late GRU bufs alias kbf AFTER k_attn2
    short* hkv = (short*)(xa + NT);
    __hip_bfloat16* kbf = (__hip_bfloat16*)hkv;
    __hip_bfloat16* vbfT = (__hip_bfloat16*)(hkv + NT);
    char* r2late = (char*)hkv;
    __hip_bfloat16* resh_bf = (__hip_bfloat16*)r2late;                // 2,097,152
    float* gi = (float*)(r2late + 2359296);                           // 1,572,864
    float* gh = (float*)(r2late + 3932160);                           // 1,572,864
    // region 3 (16.8 MB): attn-phase buffers
    short* xsp = hkv + 2 * NT;
    char* late = (char*)xsp;
    __hip_bfloat16* WihT = (__hip_bfloat16*)late;                     // 3,145,728
    __hip_bfloat16* WhhT = (__hip_bfloat16*)(late + 3145728);         //   393,216
    __hip_bfloat16* WoT  = (__hip_bfloat16*)(late + 3538944);         //   131,072
    short* WqTbf = (short*)(late + 3670016);                          //   131,072
    short* Ctx   = (short*)(late + 3801088);                          // 4,194,304
    // region 4: persistent small (never aliased)
    short* fixed = xsp + 2 * (size_t)NTOK * 64;
    short* W1Thi = fixed;                    // 16384
    short* W1Tlo = W1Thi + 16384;
    short* W2Thi = W1Tlo + 16384;            // 65536
    short* W2Tlo = W2Thi + 65536;
    float* WqT = (float*)(W2Tlo + 65536);    // 65536 floats
    __hip_bfloat16* WkvT = (__hip_bfloat16*)(WqT + 65536);  // 131072
    int* idxb = (int*)(WkvT + 131072);                      // 4096 ints
    __hip_bfloat16* pdbf = (__hip_bfloat16*)(idxb + 4096);  // 131072 bf16

    float* newd = out;                       // [B, D]
    float* resh = out + (size_t)BB * DD;     // [B, TOPK*D]

    k_prepall <<<2192, 256, 0, stream>>>(W1, W1Thi, W1Tlo, W2, W2Thi, W2Tlo,
                                         Wqkv, WqT, WqTbf, WkvT,
                                         W_ih, WihT, W_hh, WhhT, Wo, WoT,
                                         prev_d, pdbf);
    k_mlp     <<<NTOK / 32, 256, 0, stream>>>(x_obs, W1Thi, W1Tlo, b1,
                                              W2Thi, W2Tlo, b2, a_prev, xa);
    k_skv     <<<1536, 256, 0, stream>>>(xa, Wqkv, WqT, bqkv,
                                         (const short*)WkvT, idxb, kbf, vbfT);
    k_attn2   <<<BB, 256, 0, stream>>>(xa, idxb, WqTbf, bqkv,
                                       (const short*)kbf, (const short*)vbfT, Ctx);
    k_omm     <<<128, 256, 0, stream>>>(Ctx, (const short*)WoT, bo, resh, resh_bf);
    k_gru2    <<<48, 256, 0, stream>>>(resh_bf, WihT, pdbf, WhhT, gi, gh);
    k_gruact  <<<BB, 256, 0, stream>>>(gi, gh, b_ih, b_hh, prev_d, newd);
}

// Round 13
// 380.370 us; speedup vs baseline: 1.0409x; 1.0409x over previous
//
#include <hip/hip_runtime.h>
#include <hip/hip_bf16.h>
#include <math.h>

#define BB 512
#define SS 128
#define DD 256
#define HH 4
#define TOPK 8
#define D3 768
#define DMA 248
#define ACT_ 8
#define NTOK 65536            // B*S

typedef __attribute__((ext_vector_type(8))) short bf16x8;
typedef __attribute__((ext_vector_type(4))) short short4v;
typedef __attribute__((ext_vector_type(4))) float f32x4;

static __device__ __forceinline__ short f2bf(float x) {
    __hip_bfloat16 h = __float2bfloat16(x);
    return *reinterpret_cast<short*>(&h);
}
static __device__ __forceinline__ float bf2f(short s) {
    __hip_bfloat16 h = *reinterpret_cast<__hip_bfloat16*>(&s);
    return __bfloat162float(h);
}
static __device__ __forceinline__ float tanh_fast(float x) {
    float e = __expf(2.f * x);
    return 1.f - 2.f / (e + 1.f);
}

// ---------------------------------------------------------------------------
// device helpers for the merged prep kernel
// ---------------------------------------------------------------------------
__device__ __forceinline__ void dev_wsplit(float (*t)[33], const float* src,
        short* dhi, short* dlo, int R, int C, int Cpad, int blk, int tid) {
    const int ctiles = Cpad >> 5;
    const int rt = blk / ctiles, ct = blk % ctiles;
    const int r0 = rt * 32, c0 = ct * 32;
#pragma unroll
    for (int i = 0; i < 4; ++i) {
        int idx = i * 256 + tid;
        int lr = idx >> 5, lc = idx & 31;
        t[lr][lc] = (c0 + lc < C) ? src[(size_t)(r0 + lr) * C + c0 + lc] : 0.f;
    }
    __syncthreads();
#pragma unroll
    for (int i = 0; i < 4; ++i) {
        int idx = i * 256 + tid;
        int lc = idx >> 5, lr = idx & 31;
        float v = t[lr][lc];
        short h = f2bf(v);
        size_t o = (size_t)(c0 + lc) * R + r0 + lr;
        dhi[o] = h;
        dlo[o] = f2bf(v - bf2f(h));
    }
}

__device__ __forceinline__ void dev_trbf(float (*t)[33], const float* src,
        __hip_bfloat16* dst, int R, int C, int blk, int tid) {
    const int ctiles = C >> 5;
    const int rt = blk / ctiles, ct = blk % ctiles;
    const int r0 = rt * 32, c0 = ct * 32;
#pragma unroll
    for (int i = 0; i < 4; ++i) {
        int idx = i * 256 + tid;
        int lr = idx >> 5, lc = idx & 31;
        t[lr][lc] = src[(size_t)(r0 + lr) * C + c0 + lc];
    }
    __syncthreads();
#pragma unroll
    for (int i = 0; i < 4; ++i) {
        int idx = i * 256 + tid;
        int lc = idx >> 5, lr = idx & 31;
        dst[(size_t)(c0 + lc) * R + r0 + lr] = __float2bfloat16(t[lr][lc]);
    }
}

__device__ __forceinline__ void dev_prep(float (*t)[33], const float* Wqkv,
        float* WqT, short* WqTbf, __hip_bfloat16* WkvT, int blk, int tid) {
    const int rt = blk / 24, ct = blk % 24;
    const int r0 = rt * 32, c0 = ct * 32;
#pragma unroll
    for (int i = 0; i < 4; ++i) {
        int idx = i * 256 + tid;
        int lr = idx >> 5, lc = idx & 31;
        t[lr][lc] = Wqkv[(size_t)(r0 + lr) * D3 + c0 + lc];
    }
    __syncthreads();
#pragma unroll
    for (int i = 0; i < 4; ++i) {
        int idx = i * 256 + tid;
        int lc = idx >> 5, lr = idx & 31;
        float v = t[lr][lc];
        int c = c0 + lc, r = r0 + lr;
        if (c < 256) {
            WqT[(size_t)c * 256 + r] = v;
            WqTbf[(size_t)c * 256 + r] = f2bf(v);
        } else {
            WkvT[(size_t)(c - 256) * 256 + r] = __float2bfloat16(v);
        }
    }
}

// ---------------------------------------------------------------------------
// K_prepall: all weight transposes/splits + pdcast in ONE launch.
// ---------------------------------------------------------------------------
__global__ void __launch_bounds__(256) k_prepall(
        const float* __restrict__ W1, short* __restrict__ W1Thi, short* __restrict__ W1Tlo,
        const float* __restrict__ W2, short* __restrict__ W2Thi, short* __restrict__ W2Tlo,
        const float* __restrict__ Wqkv, float* __restrict__ WqT, short* __restrict__ WqTbf,
        __hip_bfloat16* __restrict__ WkvT,
        const float* __restrict__ W_ih, __hip_bfloat16* __restrict__ WihT,
        const float* __restrict__ W_hh, __hip_bfloat16* __restrict__ WhhT,
        const float* __restrict__ Wo, __hip_bfloat16* __restrict__ WoT,
        const float* __restrict__ prev_d, __hip_bfloat16* __restrict__ pdbf) {
    __shared__ float t[32][33];
    const int blk = blockIdx.x, tid = threadIdx.x;
    if (blk < 16)        dev_wsplit(t, W1, W1Thi, W1Tlo, 64, 256, 256, blk, tid);
    else if (blk < 80)   dev_wsplit(t, W2, W2Thi, W2Tlo, 256, DMA, 256, blk - 16, tid);
    else if (blk < 272)  dev_prep(t, Wqkv, WqT, WqTbf, WkvT, blk - 80, tid);
    else if (blk < 1808) dev_trbf(t, W_ih, WihT, 2048, 768, blk - 272, tid);
    else if (blk < 2000) dev_trbf(t, W_hh, WhhT, 256, 768, blk - 1808, tid);
    else if (blk < 2064) dev_trbf(t, Wo, WoT, 256, 256, blk - 2000, tid);
    else {
        int i = (blk - 2064) * 1024 + tid * 4;
        float4 v = *(const float4*)&prev_d[i];
        pdbf[i]     = __float2bfloat16(v.x);
        pdbf[i + 1] = __float2bfloat16(v.y);
        pdbf[i + 2] = __float2bfloat16(v.z);
        pdbf[i + 3] = __float2bfloat16(v.w);
    }
}

// ---------------------------------------------------------------------------
// K_mlp: FUSED MLP + K/V emit. 32 tokens/block (one batch-quarter).
// GEMM1 (x@W1,tanh) -> Hhi/Hlo LDS -> GEMM2 (h@W2 | a_prev) -> xa fp32 +
// Xbf (bf16 xa strip, reuses Hhi after barrier) -> GEMM3 (Xbf @ WkvT + bkv)
// -> kbf [b][tok][dim] / vbfT [b][dim][tok]. GEMM3 k-order matches the old
// standalone k_kvmm exactly -> bit-identical K/V.
// ---------------------------------------------------------------------------
__global__ void __launch_bounds__(256) k_mlp(const float* __restrict__ x_obs,
        const short* __restrict__ W1Thi, const short* __restrict__ W1Tlo,
        const float* __restrict__ b1,
        const short* __restrict__ W2Thi, const short* __restrict__ W2Tlo,
        const float* __restrict__ b2, const float* __restrict__ a_prev,
        const short* __restrict__ WkvT, const float* __restrict__ bqkv,
        float* __restrict__ xa,
        __hip_bfloat16* __restrict__ kbf, __hip_bfloat16* __restrict__ vbfT) {
    __shared__ __attribute__((aligned(16))) short Hhi[32 * 264];
    __shared__ __attribute__((aligned(16))) short Hlo[32 * 264];
    const int m0 = blockIdx.x * 32;
    const int b = blockIdx.x >> 2;                 // batch
    const int tb0 = (blockIdx.x & 3) * 32;          // token base within batch
    const int tid = threadIdx.x;
    const int wave = tid >> 6, lane = tid & 63;
    const int quad = lane >> 4, l15 = lane & 15;
    const int n0 = wave * 64;

    // ---- GEMM1: h strip [32 tokens x 64 cols] ----
    {
        bf16x8 Bh[4][2], Bl[4][2];
#pragma unroll
        for (int nt = 0; nt < 4; ++nt)
#pragma unroll
            for (int ks = 0; ks < 2; ++ks) {
                size_t o = (size_t)(n0 + nt * 16 + l15) * 64 + ks * 32 + quad * 8;
                Bh[nt][ks] = *(const bf16x8*)&W1Thi[o];
                Bl[nt][ks] = *(const bf16x8*)&W1Tlo[o];
            }
        f32x4 acc[2][4];
#pragma unroll
        for (int mt = 0; mt < 2; ++mt)
#pragma unroll
            for (int nt = 0; nt < 4; ++nt) acc[mt][nt] = (f32x4){0.f, 0.f, 0.f, 0.f};
#pragma unroll
        for (int mt = 0; mt < 2; ++mt) {
            bf16x8 Ah[2], Al[2];
#pragma unroll
            for (int ks = 0; ks < 2; ++ks) {
                const float* xp = &x_obs[(size_t)(m0 + mt * 16 + l15) * 64 + ks * 32 + quad * 8];
                float4 a0 = *(const float4*)xp;
                float4 a1 = *(const float4*)(xp + 4);
                bf16x8 h, l;
                h[0]=f2bf(a0.x); l[0]=f2bf(a0.x - bf2f(h[0]));
                h[1]=f2bf(a0.y); l[1]=f2bf(a0.y - bf2f(h[1]));
                h[2]=f2bf(a0.z); l[2]=f2bf(a0.z - bf2f(h[2]));
                h[3]=f2bf(a0.w); l[3]=f2bf(a0.w - bf2f(h[3]));
                h[4]=f2bf(a1.x); l[4]=f2bf(a1.x - bf2f(h[4]));
                h[5]=f2bf(a1.y); l[5]=f2bf(a1.y - bf2f(h[5]));
                h[6]=f2bf(a1.z); l[6]=f2bf(a1.z - bf2f(h[6]));
                h[7]=f2bf(a1.w); l[7]=f2bf(a1.w - bf2f(h[7]));
                Ah[ks] = h; Al[ks] = l;
            }
#pragma unroll
            for (int nt = 0; nt < 4; ++nt)
#pragma unroll
                for (int ks = 0; ks < 2; ++ks) {
                    acc[mt][nt] = __builtin_amdgcn_mfma_f32_16x16x32_bf16(Ah[ks], Bh[nt][ks], acc[mt][nt], 0, 0, 0);
                    acc[mt][nt] = __builtin_amdgcn_mfma_f32_16x16x32_bf16(Ah[ks], Bl[nt][ks], acc[mt][nt], 0, 0, 0);
                    acc[mt][nt] = __builtin_amdgcn_mfma_f32_16x16x32_bf16(Al[ks], Bh[nt][ks], acc[mt][nt], 0, 0, 0);
                }
        }
#pragma unroll
        for (int nt = 0; nt < 4; ++nt) {
            int col = n0 + nt * 16 + l15;
            float bias = b1[col];
#pragma unroll
            for (int mt = 0; mt < 2; ++mt)
#pragma unroll
                for (int r = 0; r < 4; ++r) {
                    int tl = mt * 16 + quad * 4 + r;       // local token
                    float tv = tanh_fast(acc[mt][nt][r] + bias);
                    short h = f2bf(tv);
                    Hhi[tl * 264 + col] = h;
                    Hlo[tl * 264 + col] = f2bf(tv - bf2f(h));
                }
        }
    }

    // ---- GEMM2: double-buffered B; k0=0 preload overlaps the barrier ----
    f32x4 acc[2][4];
#pragma unroll
    for (int mt = 0; mt < 2; ++mt)
#pragma unroll
        for (int nt = 0; nt < 4; ++nt) acc[mt][nt] = (f32x4){0.f, 0.f, 0.f, 0.f};

    bf16x8 Bh[2][4], Bl[2][4];
#pragma unroll
    for (int nt = 0; nt < 4; ++nt) {
        size_t o = (size_t)(n0 + nt * 16 + l15) * 256 + quad * 8;
        Bh[0][nt] = *(const bf16x8*)&W2Thi[o];
        Bl[0][nt] = *(const bf16x8*)&W2Tlo[o];
    }
    __syncthreads();

#pragma unroll
    for (int ki = 0; ki < 8; ++ki) {
        const int cur = ki & 1, nxt = cur ^ 1;
        if (ki < 7) {
            int k0n = (ki + 1) * 32;
#pragma unroll
            for (int nt = 0; nt < 4; ++nt) {
                size_t o = (size_t)(n0 + nt * 16 + l15) * 256 + k0n + quad * 8;
                Bh[nxt][nt] = *(const bf16x8*)&W2Thi[o];
                Bl[nxt][nt] = *(const bf16x8*)&W2Tlo[o];
            }
        }
        const int k0 = ki * 32;
#pragma unroll
        for (int mt = 0; mt < 2; ++mt) {
            bf16x8 Ah = *(bf16x8*)&Hhi[(mt * 16 + l15) * 264 + k0 + quad * 8];
            bf16x8 Al = *(bf16x8*)&Hlo[(mt * 16 + l15) * 264 + k0 + quad * 8];
#pragma unroll
            for (int nt = 0; nt < 4; ++nt) {
                acc[mt][nt] = __builtin_amdgcn_mfma_f32_16x16x32_bf16(Ah, Bh[cur][nt], acc[mt][nt], 0, 0, 0);
                acc[mt][nt] = __builtin_amdgcn_mfma_f32_16x16x32_bf16(Ah, Bl[cur][nt], acc[mt][nt], 0, 0, 0);
                acc[mt][nt] = __builtin_amdgcn_mfma_f32_16x16x32_bf16(Al, Bh[cur][nt], acc[mt][nt], 0, 0, 0);
            }
        }
    }

    // all waves finished READING Hhi/Hlo before we overwrite with Xbf
    __syncthreads();
    short* Xbf = Hhi;   // reuse: bf16 xa strip [32][264]
#pragma unroll
    for (int nt = 0; nt < 4; ++nt) {
        int col = n0 + nt * 16 + l15;
        float bias = (col < DMA) ? b2[col] : 0.f;
#pragma unroll
        for (int mt = 0; mt < 2; ++mt)
#pragma unroll
            for (int r = 0; r < 4; ++r) {
                int tl = mt * 16 + quad * 4 + r;
                int token = m0 + tl;
                float v;
                if (col < DMA) v = acc[mt][nt][r] + bias;
                else           v = a_prev[(size_t)token * ACT_ + (col - DMA)];
                xa[(size_t)token * 256 + col] = v;
                Xbf[tl * 264 + col] = f2bf(v);
            }
    }
    __syncthreads();

    // ---- GEMM3: K/V = Xbf @ WkvT + bkv (bit-identical to old k_kvmm) ----
    for (int ntile = 0; ntile < 4; ++ntile) {
        const int nbase = ntile * 128 + wave * 32;
        f32x4 acc3[2][2];
#pragma unroll
        for (int nf = 0; nf < 2; ++nf) {
            float bias = bqkv[256 + nbase + nf * 16 + l15];
#pragma unroll
            for (int mt = 0; mt < 2; ++mt)
                acc3[mt][nf] = (f32x4){bias, bias, bias, bias};
        }
#pragma unroll
        for (int k0 = 0; k0 < 256; k0 += 32) {
            bf16x8 af[2], bfv[2];
#pragma unroll
            for (int mt = 0; mt < 2; ++mt)
                af[mt] = *(bf16x8*)&Xbf[(mt * 16 + l15) * 264 + k0 + quad * 8];
#pragma unroll
            for (int nf = 0; nf < 2; ++nf)
                bfv[nf] = *(const bf16x8*)&WkvT[(size_t)(nbase + nf * 16 + l15) * 256 + k0 + quad * 8];
#pragma unroll
            for (int mt = 0; mt < 2; ++mt)
#pragma unroll
                for (int nf = 0; nf < 2; ++nf)
                    acc3[mt][nf] = __builtin_amdgcn_mfma_f32_16x16x32_bf16(
                        af[mt], bfv[nf], acc3[mt][nf], 0, 0, 0);
        }
#pragma unroll
        for (int nf = 0; nf < 2; ++nf) {
            int n_g = nbase + nf * 16 + l15;
#pragma unroll
            for (int mt = 0; mt < 2; ++mt)
#pragma unroll
                for (int r = 0; r < 4; ++r) {
                    int token = tb0 + mt * 16 + quad * 4 + r;
                    if (n_g < 256)
                        kbf[((size_t)b * SS + token) * 256 + n_g] = __float2bfloat16(acc3[mt][nf][r]);
                    else
                        vbfT[((size_t)b * 256 + (n_g - 256)) * SS + token] = __float2bfloat16(acc3[mt][nf][r]);
                }
        }
    }
}

// ---------------------------------------------------------------------------
// K_score: per batch: xasum -> ksum -> wqk -> fp64 score rows (coalesced,
// wave-parallel butterfly) -> wave top-8.
// ---------------------------------------------------------------------------
__global__ void __launch_bounds__(256) k_score(const float* __restrict__ xa,
        const float* __restrict__ Wqkv, const float* __restrict__ WqT,
        const float* __restrict__ bqkv, int* __restrict__ idxb) {
    __shared__ float xasum_sh[256];
    __shared__ float ksum_sh[256];
    __shared__ float wqk_sh[256];
    __shared__ double ssd[128];
    const int b = blockIdx.x;
    const int tid = threadIdx.x;
    const float* xab = xa + (size_t)b * SS * DD;

    float s = 0.f;
    for (int r = 0; r < 128; ++r) s += xab[r * 256 + tid];
    xasum_sh[tid] = s;
    __syncthreads();

    float ks = 128.f * bqkv[256 + tid];
    for (int d = 0; d < 256; ++d)
        ks = fmaf(xasum_sh[d], Wqkv[(size_t)d * D3 + 256 + tid], ks);
    ksum_sh[tid] = ks;
    __syncthreads();

    float wq = 0.f;
    for (int c = 0; c < 256; ++c)
        wq = fmaf(WqT[(size_t)c * 256 + tid], ksum_sh[c], wq);
    wqk_sh[tid] = wq;
    double bqdot = 0.0;
    for (int c = 0; c < 256; ++c)
        bqdot += (double)bqkv[c] * (double)ksum_sh[c];
    __syncthreads();

    // row dots: wave w rows [w*32, w*32+32); lane l covers cols 4l..4l+3.
    {
        const int wv = tid >> 6, lane = tid & 63;
#pragma unroll 4
        for (int rr = 0; rr < 32; ++rr) {
            int r = wv * 32 + rr;
            float4 x4 = *(const float4*)&xab[(size_t)r * 256 + lane * 4];
            const float* w4 = wqk_sh + lane * 4;
            double p = (double)x4.x * (double)w4[0];
            p += (double)x4.y * (double)w4[1];
            p += (double)x4.z * (double)w4[2];
            p += (double)x4.w * (double)w4[3];
#pragma unroll
            for (int off = 1; off < 64; off <<= 1) p += __shfl_xor(p, off);
            if (lane == 0) ssd[r] = (p + bqdot) * 0.125;
        }
    }
    __syncthreads();
    if (tid < 64) {
        double v0 = ssd[tid], v1 = ssd[tid + 64];
        int i0 = tid, i1 = tid + 64;
        bool t0 = false, t1 = false;
        for (int t = 0; t < TOPK; ++t) {
            double c0 = t0 ? -1e300 : v0;
            double c1 = t1 ? -1e300 : v1;
            double bvv; int bi;
            if (c1 > c0) { bvv = c1; bi = i1; } else { bvv = c0; bi = i0; }
#pragma unroll
            for (int off = 1; off < 64; off <<= 1) {
                double ov = __shfl_xor(bvv, off);
                int oi = __shfl_xor(bi, off);
                if (ov > bvv || (ov == bvv && oi < bi)) { bvv = ov; bi = oi; }
            }
            if (tid == 0) idxb[b * TOPK + t] = bi;
            if (bi == i0) t0 = true;
            if (bi == i1) t1 = true;
        }
    }
}

// ---------------------------------------------------------------------------
// K_attn2: gather + q-projection + attention fused, per batch. Wave = head.
// ---------------------------------------------------------------------------
__global__ void __launch_bounds__(256) k_attn2(const float* __restrict__ xa,
        const int* __restrict__ idxb, const short* __restrict__ WqTbf,
        const float* __restrict__ bqkv,
        const short* __restrict__ kbf, const short* __restrict__ vbfT,
        short* __restrict__ Ctx) {
    __shared__ __attribute__((aligned(16))) short Xsh[16 * 264];
    __shared__ __attribute__((aligned(16))) short Qsh[16 * 264];
    __shared__ short Pbuf[4][16 * 136];
    __shared__ int sidx[8];
    const int b = blockIdx.x;
    const int tid = threadIdx.x;
    const int h = tid >> 6, lane = tid & 63;
    const int quad = lane >> 4, l15 = lane & 15;

    if (tid < 8) sidx[tid] = idxb[b * TOPK + tid];
    __syncthreads();
#pragma unroll
    for (int t = 0; t < 16; ++t) {
        short v = 0;
        if (t < 8) v = f2bf(xa[((size_t)b * SS + sidx[t]) * 256 + tid]);
        Xsh[t * 264 + tid] = v;
    }
    __syncthreads();

    {
        f32x4 qacc[4];
#pragma unroll
        for (int nt = 0; nt < 4; ++nt) qacc[nt] = (f32x4){0.f, 0.f, 0.f, 0.f};
#pragma unroll
        for (int ki = 0; ki < 8; ++ki) {
            int k0 = ki * 32;
            bf16x8 Ax = *(bf16x8*)&Xsh[l15 * 264 + k0 + quad * 8];
#pragma unroll
            for (int nt = 0; nt < 4; ++nt) {
                int col = h * 64 + nt * 16 + l15;
                bf16x8 Bq = *(const bf16x8*)&WqTbf[(size_t)col * 256 + k0 + quad * 8];
                qacc[nt] = __builtin_amdgcn_mfma_f32_16x16x32_bf16(Ax, Bq, qacc[nt], 0, 0, 0);
            }
        }
#pragma unroll
        for (int nt = 0; nt < 4; ++nt) {
            int col = h * 64 + nt * 16 + l15;
            float bq = bqkv[col];
#pragma unroll
            for (int r = 0; r < 4; ++r)
                Qsh[(quad * 4 + r) * 264 + col] = f2bf(qacc[nt][r] + bq);
        }
    }
    // Qsh strip is wave-local — no barrier needed.

    const short* kb = kbf + (size_t)b * SS * 256 + h * 64;
    const short* vb = vbfT + ((size_t)b * 256 + h * 64) * SS;

    bf16x8 aq[2];
#pragma unroll
    for (int ks = 0; ks < 2; ++ks)
        aq[ks] = *(bf16x8*)&Qsh[l15 * 264 + h * 64 + ks * 32 + quad * 8];
    f32x4 sc[8];
#pragma unroll
    for (int nt = 0; nt < 8; ++nt) sc[nt] = (f32x4){0.f, 0.f, 0.f, 0.f};
#pragma unroll
    for (int nt = 0; nt < 8; ++nt)
#pragma unroll
        for (int ks = 0; ks < 2; ++ks) {
            bf16x8 bk = *(const bf16x8*)&kb[(size_t)(nt * 16 + l15) * 256 + ks * 32 + quad * 8];
            sc[nt] = __builtin_amdgcn_mfma_f32_16x16x32_bf16(aq[ks], bk, sc[nt], 0, 0, 0);
        }
#pragma unroll
    for (int r = 0; r < 4; ++r) {
        float m = -3.4e38f;
#pragma unroll
        for (int nt = 0; nt < 8; ++nt) m = fmaxf(m, sc[nt][r]);
        m = fmaxf(m, __shfl_xor(m, 1));
        m = fmaxf(m, __shfl_xor(m, 2));
        m = fmaxf(m, __shfl_xor(m, 4));
        m = fmaxf(m, __shfl_xor(m, 8));
        float s = 0.f;
#pragma unroll
        for (int nt = 0; nt < 8; ++nt) {
            float e = __expf((sc[nt][r] - m) * 0.125f);
            sc[nt][r] = e;
            s += e;
        }
        s += __shfl_xor(s, 1);
        s += __shfl_xor(s, 2);
        s += __shfl_xor(s, 4);
        s += __shfl_xor(s, 8);
        float inv = 1.f / s;
        int row = quad * 4 + r;
#pragma unroll
        for (int nt = 0; nt < 8; ++nt)
            Pbuf[h][row * 136 + nt * 16 + l15] = f2bf(sc[nt][r] * inv);
    }
    __syncthreads();
    bf16x8 ap[4];
#pragma unroll
    for (int ks = 0; ks < 4; ++ks)
        ap[ks] = *(bf16x8*)&Pbuf[h][l15 * 136 + ks * 32 + quad * 8];
    f32x4 ct[4];
#pragma unroll
    for (int nt = 0; nt < 4; ++nt) ct[nt] = (f32x4){0.f, 0.f, 0.f, 0.f};
#pragma unroll
    for (int nt = 0; nt < 4; ++nt)
#pragma unroll
        for (int ks = 0; ks < 4; ++ks) {
            bf16x8 bv = *(const bf16x8*)&vb[(size_t)(nt * 16 + l15) * SS + ks * 32 + quad * 8];
            ct[nt] = __builtin_amdgcn_mfma_f32_16x16x32_bf16(ap[ks], bv, ct[nt], 0, 0, 0);
        }
#pragma unroll
    for (int nt = 0; nt < 4; ++nt)
#pragma unroll
        for (int r = 0; r < 4; ++r)
            Ctx[((size_t)b * 16 + quad * 4 + r) * 256 + h * 64 + nt * 16 + l15] =
                f2bf(ct[nt][r]);
}

// ---------------------------------------------------------------------------
// K_omm: resh = Ctx @ WoT^T + bo. Writes fp32 resh (d_out) + bf16 resh_bf.
// ---------------------------------------------------------------------------
__global__ void __launch_bounds__(256) k_omm(const short* __restrict__ A,
        const short* __restrict__ BT, const float* __restrict__ bias,
        float* __restrict__ resh_out, __hip_bfloat16* __restrict__ resh_bf) {
    __shared__ __attribute__((aligned(16))) short Ash[128 * 72];
    __shared__ __attribute__((aligned(16))) short Bsh[128 * 72];
    const int mt = blockIdx.x >> 1, nt2 = blockIdx.x & 1;
    const int m0 = mt * 128, n0 = nt2 * 128;
    const int tid = threadIdx.x;
    const int wave = tid >> 6, lane = tid & 63;
    const int wm = wave >> 1, wn = wave & 1;
    const int quad = lane >> 4, l15 = lane & 15;

    f32x4 acc[4][4];
#pragma unroll
    for (int tm = 0; tm < 4; ++tm)
#pragma unroll
        for (int tn = 0; tn < 4; ++tn) acc[tm][tn] = (f32x4){0.f, 0.f, 0.f, 0.f};

    for (int k0 = 0; k0 < 256; k0 += 64) {
        __syncthreads();
#pragma unroll
        for (int it = 0; it < 4; ++it) {
            int idx = it * 256 + tid;
            int row = idx >> 3, c8 = idx & 7;
            *(uint4*)&Ash[row * 72 + c8 * 8] =
                *(const uint4*)&A[(size_t)(m0 + row) * 256 + k0 + c8 * 8];
            *(uint4*)&Bsh[row * 72 + c8 * 8] =
                *(const uint4*)&BT[(size_t)(n0 + row) * 256 + k0 + c8 * 8];
        }
        __syncthreads();
#pragma unroll
        for (int ks = 0; ks < 2; ++ks) {
            bf16x8 af[4], bfr[4];
#pragma unroll
            for (int t = 0; t < 4; ++t) {
                af[t]  = *(bf16x8*)&Ash[(wm * 64 + t * 16 + l15) * 72 + ks * 32 + quad * 8];
                bfr[t] = *(bf16x8*)&Bsh[(wn * 64 + t * 16 + l15) * 72 + ks * 32 + quad * 8];
            }
#pragma unroll
            for (int tm = 0; tm < 4; ++tm)
#pragma unroll
                for (int tn = 0; tn < 4; ++tn)
                    acc[tm][tn] = __builtin_amdgcn_mfma_f32_16x16x32_bf16(
                        af[tm], bfr[tn], acc[tm][tn], 0, 0, 0);
        }
    }
#pragma unroll
    for (int tm = 0; tm < 4; ++tm)
#pragma unroll
        for (int tn = 0; tn < 4; ++tn) {
            int col = n0 + wn * 64 + tn * 16 + l15;
            float bv = bias[col];
#pragma unroll
            for (int r = 0; r < 4; ++r) {
                int row = m0 + wm * 64 + tm * 16 + quad * 4 + r;
                int bidx = row >> 4, r16 = row & 15;
                if (r16 < 8) {
                    float v = acc[tm][tn][r] + bv;
                    size_t o = (size_t)bidx * 2048 + r16 * 256 + col;
                    resh_out[o] = v;
                    resh_bf[o] = __float2bfloat16(v);
                }
            }
        }
}

// ---------------------------------------------------------------------------
// K_gru2: both GRU GEMMs in one launch. blocks [0,24): gi (K=2048);
// blocks [24,48): gh (K=256). N=768, 128x128 tiles.
// ---------------------------------------------------------------------------
__global__ void __launch_bounds__(256) k_gru2(const __hip_bfloat16* __restrict__ resh_bf,
        const __hip_bfloat16* __restrict__ WihT, const __hip_bfloat16* __restrict__ pdbf,
        const __hip_bfloat16* __restrict__ WhhT, float* __restrict__ gi,
        float* __restrict__ gh) {
    __shared__ __attribute__((aligned(16))) short Ash[128 * 72];
    __shared__ __attribute__((aligned(16))) short Bsh[128 * 72];
    int blk = blockIdx.x;
    const __hip_bfloat16 *A, *BT;
    float* C;
    int K;
    if (blk < 24) { A = resh_bf; BT = WihT; C = gi; K = 2048; }
    else          { blk -= 24; A = pdbf; BT = WhhT; C = gh; K = 256; }
    const int mt = blk / 6, nt = blk % 6;
    const int m0 = mt * 128, n0 = nt * 128;
    const int tid = threadIdx.x;
    const int wave = tid >> 6, lane = tid & 63;
    const int wm = wave >> 1, wn = wave & 1;
    const int quad = lane >> 4, l15 = lane & 15;

    f32x4 acc[4][4];
#pragma unroll
    for (int tm = 0; tm < 4; ++tm)
#pragma unroll
        for (int tn = 0; tn < 4; ++tn)
            acc[tm][tn] = (f32x4){0.f, 0.f, 0.f, 0.f};

    for (int k0 = 0; k0 < K; k0 += 64) {
        __syncthreads();
#pragma unroll
        for (int it = 0; it < 4; ++it) {
            int idx = it * 256 + tid;
            int row = idx >> 3, c8 = idx & 7;
            *(uint4*)&Ash[row * 72 + c8 * 8] =
                *(const uint4*)&A[(size_t)(m0 + row) * K + k0 + c8 * 8];
            *(uint4*)&Bsh[row * 72 + c8 * 8] =
                *(const uint4*)&BT[(size_t)(n0 + row) * K + k0 + c8 * 8];
        }
        __syncthreads();
#pragma unroll
        for (int ks = 0; ks < 2; ++ks) {
            bf16x8 af[4], bfr[4];
#pragma unroll
            for (int t = 0; t < 4; ++t) {
                af[t]  = *(bf16x8*)&Ash[(wm * 64 + t * 16 + l15) * 72 + ks * 32 + quad * 8];
                bfr[t] = *(bf16x8*)&Bsh[(wn * 64 + t * 16 + l15) * 72 + ks * 32 + quad * 8];
            }
#pragma unroll
            for (int tm = 0; tm < 4; ++tm)
#pragma unroll
                for (int tn = 0; tn < 4; ++tn)
                    acc[tm][tn] = __builtin_amdgcn_mfma_f32_16x16x32_bf16(
                        af[tm], bfr[tn], acc[tm][tn], 0, 0, 0);
        }
    }
#pragma unroll
    for (int tm = 0; tm < 4; ++tm)
#pragma unroll
        for (int tn = 0; tn < 4; ++tn) {
            int col = n0 + wn * 64 + tn * 16 + l15;
#pragma unroll
            for (int r = 0; r < 4; ++r) {
                int row = m0 + wm * 64 + tm * 16 + quad * 4 + r;
                C[(size_t)row * 768 + col] = acc[tm][tn][r];
            }
        }
}

// ---------------------------------------------------------------------------
// K_gruact: gates elementwise. newd = (1-z)*n + z*prev_d
// ---------------------------------------------------------------------------
__global__ void k_gruact(const float* __restrict__ gi, const float* __restrict__ gh,
                         const float* __restrict__ b_ih, const float* __restrict__ b_hh,
                         const float* __restrict__ prev_d, float* __restrict__ newd) {
    const int b = blockIdx.x, tid = threadIdx.x;
    const float* gib = gi + (size_t)b * D3;
    const float* ghb = gh + (size_t)b * D3;
    float ir = gib[tid] + b_ih[tid];
    float iz = gib[256 + tid] + b_ih[256 + tid];
    float in = gib[512 + tid] + b_ih[512 + tid];
    float hr = ghb[tid] + b_hh[tid];
    float hz = ghb[256 + tid] + b_hh[256 + tid];
    float hn = ghb[512 + tid] + b_hh[512 + tid];
    float pd = prev_d[(size_t)b * 256 + tid];
    float r = 1.f / (1.f + __expf(-(ir + hr)));
    float z = 1.f / (1.f + __expf(-(iz + hz)));
    float n = tanhf(in + r * hn);
    newd[(size_t)b * 256 + tid] = (1.f - z) * n + z * pd;
}

// ---------------------------------------------------------------------------
extern "C" void kernel_launch(void* const* d_in, const int* in_sizes, int n_in,
                              void* d_out, int out_size, void* d_ws, size_t ws_size,
                              hipStream_t stream) {
    const float* prev_d = (const float*)d_in[0];
    const float* x_obs  = (const float*)d_in[1];
    const float* a_prev = (const float*)d_in[2];
    const float* W1     = (const float*)d_in[3];
    const float* b1     = (const float*)d_in[4];
    const float* W2     = (const float*)d_in[5];
    const float* b2     = (const float*)d_in[6];
    const float* Wqkv   = (const float*)d_in[7];
    const float* bqkv   = (const float*)d_in[8];
    const float* Wo     = (const float*)d_in[9];
    const float* bo     = (const float*)d_in[10];
    const float* W_ih   = (const float*)d_in[11];
    const float* b_ih   = (const float*)d_in[12];
    const float* W_hh   = (const float*)d_in[13];
    const float* b_hh   = (const float*)d_in[14];
    float* out = (float*)d_out;

    const size_t NT = (size_t)BB * SS * DD;   // 16,777,216
    // region 1: xa fp32 (67 MB)
    float* xa = (float*)d_ws;
    // region 2 (67 MB): [kbf|vbfT]; late GRU bufs alias kbf AFTER k_attn2
    short* hkv = (short*)(xa + NT);
    __hip_bfloat16* kbf = (__hip_bfloat16*)hkv;
    __hip_bfloat16* vbfT = (__hip_bfloat16*)(hkv + NT);
    char* r2late = (char*)hkv;
    __hip_bfloat16* resh_bf = (__hip_bfloat16*)r2late;                // 2,097,152
    float* gi = (float*)(r2late + 2359296);                           // 1,572,864
    float* gh = (float*)(r2late + 3932160);                           // 1,572,864
    // region 3 (16.8 MB): attn-phase buffers
    short* xsp = hkv + 2 * NT;
    char* late = (char*)xsp;
    __hip_bfloat16* WihT = (__hip_bfloat16*)late;                     // 3,145,728
    __hip_bfloat16* WhhT = (__hip_bfloat16*)(late + 3145728);         //   393,216
    __hip_bfloat16* WoT  = (__hip_bfloat16*)(late + 3538944);         //   131,072
    short* WqTbf = (short*)(late + 3670016);                          //   131,072
    short* Ctx   = (short*)(late + 3801088);                          // 4,194,304
    // region 4: persistent small (never aliased)
    short* fixed = xsp + 2 * (size_t)NTOK * 64;
    short* W1Thi = fixed;                    // 16384
    short* W1Tlo = W1Thi + 16384;
    short* W2Thi = W1Tlo + 16384;            // 65536
    short* W2Tlo = W2Thi + 65536;
    float* WqT = (float*)(W2Tlo + 65536);    // 65536 floats
    __hip_bfloat16* WkvT = (__hip_bfloat16*)(WqT + 65536);  // 131072
    int* idxb = (int*)(WkvT + 131072);                      // 4096 ints
    __hip_bfloat16* pdbf = (__hip_bfloat16*)(idxb + 4096);  // 131072 bf16

    float* newd = out;                       // [B, D]
    float* resh = out + (size_t)BB * DD;     // [B, TOPK*D]

    k_prepall <<<2192, 256, 0, stream>>>(W1, W1Thi, W1Tlo, W2, W2Thi, W2Tlo,
                                         Wqkv, WqT, WqTbf, WkvT,
                                         W_ih, WihT, W_hh, WhhT, Wo, WoT,
                                         prev_d, pdbf);
    k_mlp     <<<NTOK / 32, 256, 0, stream>>>(x_obs, W1Thi, W1Tlo, b1,
                                              W2Thi, W2Tlo, b2, a_prev,
                                              (const short*)WkvT, bqkv,
                                              xa, kbf, vbfT);
    k_score   <<<BB, 256, 0, stream>>>(xa, Wqkv, WqT, bqkv, idxb);
    k_attn2   <<<BB, 256, 0, stream>>>(xa, idxb, WqTbf, bqkv,
                                       (const short*)kbf, (const short*)vbfT, Ctx);
    k_omm     <<<128, 256, 0, stream>>>(Ctx, (const short*)WoT, bo, resh, resh_bf);
    k_gru2    <<<48, 256, 0, stream>>>(resh_bf, WihT, pdbf, WhhT, gi, gh);
    k_gruact  <<<BB, 256, 0, stream>>>(gi, gh, b_ih, b_hh, prev_d, newd);
}